// Round 8
// baseline (114.137 us; speedup 1.0000x reference)
//
#include <hip/hip_runtime.h>
#include <cstdint>
#include <cstddef>

// PointNet++ FP, bf16-MFMA pipeline v6: occupancy-slim front.
// B=8, N=4096, S=1024, D1=128, D2=256, IN_C=384, MLP=[256,256], BN training.
//
//  front:  ONE kernel (17.7 KB LDS -> 8 blocks/CU), block-role dispatch:
//            [0,1024)      top3 (8 lanes/query, branchless + shfl_xor merge)
//            [1024,3072)   transpose points2 -> p2b bf16 [B][S][256]
//            [3072,5120)   transpose colors2 -> c2b bf16
//            [5120,5440)   convw: W* -> bf16 [o][k]
//            [5440,6464)   buildxA: points1/colors1 -> Xp bf16 (2-phase, 69-pad)
//  gemm1f: 256m x 256c, 8 waves, LDS dbuf prefetch; xcd=wg&7, t=xcd&1
//  reduce(0); gemm2f: B = relu(bn(Y1)); y2b bf16 + stats; reduce(1024)
//  bnT: LDS-transpose + relu(bn) -> d_out [t][b][o][n] fp32
//
// ws layout (bytes), total 68,952,064:
//   y2b @0 (33.5M) overlays: Xp@0 | p2b@16777216 | c2b@20971520
//     | idxw@25165824 | wgtw@25559040
//   Y1 @33554432 | Wb1 @67108864 | Wb2 @67895296
//   psum @68419584 | psq @68681728 | ssb @68943872

#define B_   8
#define N_   4096
#define S_   1024
#define D1_  128
#define D2_  256
#define INC_ 384
#define OC_  256
#define M_   (B_ * N_)

typedef __attribute__((ext_vector_type(8))) short sh8;
typedef __attribute__((ext_vector_type(4))) float f32x4;
typedef __attribute__((ext_vector_type(4))) unsigned short ush4;
typedef __attribute__((ext_vector_type(8))) unsigned short ush8;

__device__ __forceinline__ unsigned short bf16rne(float f) {
    union { float f; unsigned u; } v; v.f = f;
    return (unsigned short)((v.u + 0x7FFFu + ((v.u >> 16) & 1u)) >> 16);
}
__device__ __forceinline__ float bf2f(unsigned short h) {
    union { unsigned u; float f; } v; v.u = ((unsigned)h) << 16;
    return v.f;
}
__device__ __forceinline__ void gload16(const void* gsrc, void* lds) {
    __builtin_amdgcn_global_load_lds(
        (const __attribute__((address_space(1))) void*)gsrc,
        (__attribute__((address_space(3))) void*)lds, 16, 0, 0);
}

// ---------------------------------------------------------------- front
#define INS(pd, pi) { \
    bool l0 = (pd < d0) || (pd == d0 && pi < i0); \
    bool l1 = (pd < d1) || (pd == d1 && pi < i1); \
    bool l2 = (pd < d2) || (pd == d2 && pi < i2); \
    d2 = l1 ? d1 : (l2 ? pd : d2);  i2 = l1 ? i1 : (l2 ? pi : i2); \
    d1 = l0 ? d0 : (l1 ? pd : d1);  i1 = l0 ? i0 : (l1 ? pi : i1); \
    d0 = l0 ? pd : d0;              i0 = l0 ? pi : i0; \
}

__global__ __launch_bounds__(256) void front_kernel(
    const float* __restrict__ xyz1, const float* __restrict__ xyz2,
    const float* __restrict__ points1, const float* __restrict__ colors1,
    const float* __restrict__ points2, const float* __restrict__ colors2,
    const float* __restrict__ Wp1, const float* __restrict__ Wc1,
    const float* __restrict__ Wp2, const float* __restrict__ Wc2,
    int* __restrict__ idxo, float* __restrict__ wo,
    unsigned short* __restrict__ p2b, unsigned short* __restrict__ c2b,
    unsigned short* __restrict__ Wb1, unsigned short* __restrict__ Wb2,
    unsigned short* __restrict__ Xp)
{
    __shared__ __align__(16) char fsm[17664];   // max(top3 16K, tileA 64*69*4)
    const int bid = blockIdx.x;
    const int tid = threadIdx.x;

    if (bid < 1024) {
        // ---- top-3 NN (critical path first)
        float4* sc = (float4*)fsm;
        const int b = bid >> 7, qb = bid & 127;
        const float* x2 = xyz2 + (size_t)b * 3 * S_;
        for (int s = tid; s < S_; s += 256) {
            float xs = x2[s], ys = x2[S_ + s], zs = x2[2 * S_ + s];
            sc[s] = make_float4(xs, ys, zs, xs * xs + ys * ys + zs * zs);
        }
        __syncthreads();
        const int q = qb * 32 + (tid >> 3);
        const int sub = tid & 7;
        const float* x1 = xyz1 + (size_t)b * 3 * N_;
        const float xq = x1[q], yq = x1[N_ + q], zq = x1[2 * N_ + q];
        const float n1 = xq * xq + yq * yq + zq * zq;
        float d0 = 3.4e38f, d1 = 3.4e38f, d2 = 3.4e38f;
        int i0 = 0, i1 = 0, i2 = 0;
#pragma unroll 4
        for (int j = 0; j < 128; ++j) {
            int s = j * 8 + sub;
            float4 v = sc[s];
            float dot = xq * v.x + yq * v.y + zq * v.z;
            float d = (n1 - 2.0f * dot) + v.w;
            bool c0 = d < d0, c1 = d < d1, c2 = d < d2;
            d2 = c1 ? d1 : (c2 ? d : d2); i2 = c1 ? i1 : (c2 ? s : i2);
            d1 = c0 ? d0 : (c1 ? d : d1); i1 = c0 ? i0 : (c1 ? s : i1);
            d0 = c0 ? d : d0;             i0 = c0 ? s : i0;
        }
#pragma unroll
        for (int off = 1; off < 8; off <<= 1) {
            float pd0 = __shfl_xor(d0, off), pd1 = __shfl_xor(d1, off), pd2 = __shfl_xor(d2, off);
            int   pi0 = __shfl_xor(i0, off), pi1 = __shfl_xor(i1, off), pi2 = __shfl_xor(i2, off);
            INS(pd0, pi0) INS(pd1, pi1) INS(pd2, pi2)
        }
        if (sub == 0) {
            float r0 = 1.f / (d0 + 1e-8f);
            float r1 = 1.f / (d1 + 1e-8f);
            float r2 = 1.f / (d2 + 1e-8f);
            float rs = r0 + r1 + r2;
            int base = (b * N_ + q) * 3;
            idxo[base] = i0; idxo[base + 1] = i1; idxo[base + 2] = i2;
            wo[base] = r0 / rs; wo[base + 1] = r1 / rs; wo[base + 2] = r2 / rs;
        }
    } else if (bid < 5120) {
        // ---- transpose points2/colors2 -> bf16 [B][S][256]
        float (*tile)[33] = (float(*)[33])fsm;
        const int u = bid - 1024;
        const int which = u >> 11;                 // 0: points2, 1: colors2
        const int v = u & 2047;
        const int z = v >> 8, rem = v & 255;
        const int cx = rem & 31, ry = rem >> 5;
        const int tx = tid & 31, ty = tid >> 5;
        const float* s = (which ? colors2 : points2) + (size_t)z * D2_ * S_;
        unsigned short* d = (which ? c2b : p2b) + (size_t)z * S_ * D2_;
#pragma unroll
        for (int i = 0; i < 4; ++i)
            tile[ty + i * 8][tx] = s[(size_t)(ry * 32 + ty + i * 8) * S_ + cx * 32 + tx];
        __syncthreads();
#pragma unroll
        for (int i = 0; i < 4; ++i)
            d[(size_t)(cx * 32 + ty + i * 8) * D2_ + ry * 32 + tx] =
                bf16rne(tile[tx][ty + i * 8]);
    } else if (bid < 5440) {
        // ---- convw
        int e = ((bid - 5120) * 256 + tid) * 4;
        const float* src; unsigned short* dst; int off;
        if (e < 98304)       { src = Wp1; dst = Wb1;          off = e; }
        else if (e < 196608) { src = Wc1; dst = Wb1 + 98304;  off = e - 98304; }
        else if (e < 262144) { src = Wp2; dst = Wb2;          off = e - 196608; }
        else                 { src = Wc2; dst = Wb2 + 65536;  off = e - 262144; }
        float4 v = *(const float4*)(src + off);
        ush4 o; o[0] = bf16rne(v.x); o[1] = bf16rne(v.y); o[2] = bf16rne(v.z); o[3] = bf16rne(v.w);
        *(ush4*)(dst + off) = o;
    } else {
        // ---- buildxA: transpose points1/colors1 -> Xp bf16, 2-phase (64 d each)
        float (*tileA)[69] = (float(*)[69])fsm;
        const int u = bid - 5440;
        const int t = u >> 9, rem = u & 511;
        const int b = rem >> 6, n0 = (rem & 63) * 64;
        const float* x1 = t ? colors1 : points1;
        size_t mbase = (size_t)t * M_ + (size_t)b * N_ + n0;
#pragma unroll
        for (int ph = 0; ph < 2; ++ph) {
            if (ph) __syncthreads();
#pragma unroll
            for (int it = 0; it < 4; ++it) {
                int fl4 = it * 256 + tid;
                int dl = fl4 >> 4, nl = (fl4 & 15) * 4;
                float4 v = *(const float4*)(x1 + ((size_t)b * D1_ + ph * 64 + dl) * N_ + n0 + nl);
                tileA[nl][dl] = v.x; tileA[nl + 1][dl] = v.y;
                tileA[nl + 2][dl] = v.z; tileA[nl + 3][dl] = v.w;
            }
            __syncthreads();
#pragma unroll
            for (int it = 0; it < 2; ++it) {
                int e8 = it * 256 + tid;
                int r = e8 >> 3, dc = (e8 & 7) * 8;
                ush8 o;
#pragma unroll
                for (int j = 0; j < 8; ++j) o[j] = bf16rne(tileA[r][dc + j]);
                *(ush8*)(Xp + (mbase + r) * D1_ + ph * 64 + dc) = o;
            }
        }
    }
}

// ---------------------------------------------------------------- GEMM1 (prefetch dbuf)
// 1-D grid 256; xcd = wg&7, t = xcd&1 -> per-XCD L2 caches one gather tensor.
__global__ __launch_bounds__(512, 2) void gemm1f_kernel(
    const unsigned short* __restrict__ Xp,
    const unsigned short* __restrict__ p2b,
    const unsigned short* __restrict__ c2b,
    const int* __restrict__ idxw, const float* __restrict__ wgtw,
    const unsigned short* __restrict__ Wb1,
    unsigned short* __restrict__ Y1,
    float* __restrict__ psum, float* __restrict__ psq)
{
    const int wg  = blockIdx.x;
    const int xcd = wg & 7;
    const int t   = xcd & 1;
    const int mt  = (xcd >> 1) * 32 + (wg >> 3);   // 0..127, bijective
    const int m0  = mt * 256;
    const int bb  = m0 >> 12;
    const unsigned short* Aw  = Wb1 + (size_t)t * (OC_ * INC_);
    const unsigned short* Xb  = Xp + (size_t)t * M_ * D1_;
    const unsigned short* f2b = t ? c2b : p2b;

    __shared__ __align__(16) char smem[131072];

    const int tid  = threadIdx.x;
    const int lane = tid & 63;
    const int wid  = tid >> 6;
    const int wc   = wid & 3;
    const int wm   = wid >> 2;
    const int srow = tid >> 3;
    const int k8   = (tid & 7) * 8;
    const int sk   = ((tid & 7) ^ (srow & 7)) * 8;
    const int kgrp = (lane >> 4) * 16;

    int gi[4][3]; float gw[4][3];
#pragma unroll
    for (int p = 0; p < 4; ++p) {
        int base = (m0 + p * 64 + srow) * 3;
#pragma unroll
        for (int j = 0; j < 3; ++j) { gi[p][j] = idxw[base + j]; gw[p][j] = wgtw[base + j]; }
    }

    f32x4 acc[4][8];
#pragma unroll
    for (int i = 0; i < 4; ++i)
#pragma unroll
        for (int j = 0; j < 8; ++j) acc[i][j] = f32x4{0.f, 0.f, 0.f, 0.f};

    auto stageA = [&](int buf, int kc) {
#pragma unroll
        for (int p = 0; p < 4; ++p)
            gload16(Aw + (size_t)(p * 64 + srow) * INC_ + kc + sk,
                    smem + buf * 32768 + p * 8192 + wid * 1024);
    };
    auto stageBX = [&](int buf, int kc) {
#pragma unroll
        for (int p = 0; p < 4; ++p)
            gload16(Xb + (size_t)(m0 + p * 64 + srow) * D1_ + kc + sk,
                    smem + 65536 + buf * 32768 + p * 8192 + wid * 1024);
    };
    auto stageBG = [&](int buf, int kc) {
        const int d0k = kc - D1_ + k8;
#pragma unroll
        for (int p = 0; p < 4; ++p) {
            int row = p * 64 + srow;
            ush8 a0 = *(const ush8*)(f2b + ((size_t)bb * S_ + gi[p][0]) * D2_ + d0k);
            ush8 a1 = *(const ush8*)(f2b + ((size_t)bb * S_ + gi[p][1]) * D2_ + d0k);
            ush8 a2 = *(const ush8*)(f2b + ((size_t)bb * S_ + gi[p][2]) * D2_ + d0k);
            ush8 ov;
#pragma unroll
            for (int j = 0; j < 8; ++j)
                ov[j] = bf16rne(gw[p][0] * bf2f(a0[j]) + gw[p][1] * bf2f(a1[j])
                              + gw[p][2] * bf2f(a2[j]));
            *(ush8*)(smem + 65536 + buf * 32768 + row * 128
                     + ((k8 * 2) ^ ((row & 7) << 4))) = ov;
        }
    };
    auto compute = [&](int buf) {
#pragma unroll
        for (int kk = 0; kk < 2; ++kk) {
            sh8 a[4], b[8];
#pragma unroll
            for (int f = 0; f < 4; ++f) {
                int ra = wc * 64 + (lane & 15) + f * 16;
                a[f] = *(const sh8*)(smem + buf * 32768 + ra * 128
                        + ((kk * 64 + kgrp) ^ ((ra & 7) << 4)));
            }
#pragma unroll
            for (int f = 0; f < 8; ++f) {
                int rb = wm * 128 + (lane & 15) + f * 16;
                b[f] = *(const sh8*)(smem + 65536 + buf * 32768 + rb * 128
                        + ((kk * 64 + kgrp) ^ ((rb & 7) << 4)));
            }
#pragma unroll
            for (int fc = 0; fc < 4; ++fc)
#pragma unroll
                for (int fm = 0; fm < 8; ++fm)
                    acc[fc][fm] = __builtin_amdgcn_mfma_f32_16x16x32_bf16(
                        a[fc], b[fm], acc[fc][fm], 0, 0, 0);
        }
    };

    stageA(0, 0); stageBX(0, 0);
    __syncthreads();
    int cur = 0;
    for (int step = 0; step < 6; ++step) {
        int kcn = (step + 1) * 64;
        if (step < 5) {
            stageA(cur ^ 1, kcn);
            if (kcn < D1_) stageBX(cur ^ 1, kcn);
            else           stageBG(cur ^ 1, kcn);
        }
        compute(cur);
        __syncthreads();
        cur ^= 1;
    }

    const int mrow = m0 + wm * 128 + (lane & 15);
    const int chq  = (lane >> 4) * 4;
#pragma unroll
    for (int fm = 0; fm < 8; ++fm)
#pragma unroll
        for (int fc = 0; fc < 4; ++fc) {
            ush4 v;
#pragma unroll
            for (int r = 0; r < 4; ++r) v[r] = bf16rne(acc[fc][fm][r]);
            *(ush4*)(Y1 + ((size_t)t * M_ + mrow + fm * 16) * OC_
                      + wc * 64 + fc * 16 + chq) = v;
        }

    float* sArr = (float*)smem;
    const int contrib = wm * 16 + (lane & 15);
#pragma unroll
    for (int ph = 0; ph < 2; ++ph) {
#pragma unroll
        for (int fc = 0; fc < 4; ++fc) {
            f32x4 s4;
#pragma unroll
            for (int r = 0; r < 4; ++r) {
                float s = 0.f;
#pragma unroll
                for (int fm = 0; fm < 8; ++fm) { float v = acc[fc][fm][r]; s += ph ? v * v : v; }
                s4[r] = s;
            }
            *(f32x4*)&sArr[contrib * 264 + wc * 64 + fc * 16 + chq] = s4;
        }
        __syncthreads();
        if (tid < 256) {
            float s = 0.f;
#pragma unroll
            for (int k = 0; k < 32; ++k) s += sArr[((k + tid) & 31) * 264 + tid];
            (ph ? psq : psum)[((size_t)t * 128 + mt) * 256 + tid] = s;
        }
        __syncthreads();
    }
}

// ---------------------------------------------------------------- stats reduce
__global__ __launch_bounds__(256) void reduce_kernel(
    const float* __restrict__ psum, const float* __restrict__ psq,
    const float* __restrict__ gp, const float* __restrict__ bep,
    const float* __restrict__ gc, const float* __restrict__ bec,
    float* __restrict__ ss, int layerOff)
{
    const int t = blockIdx.x, cs = blockIdx.y;
    const int tid = threadIdx.x;
    const int cl = tid & 63, grp = tid >> 6;
    const int c = cs * 64 + cl;
    float s = 0.f, q = 0.f;
    for (int k = grp; k < 128; k += 4) {
        s += psum[((size_t)t * 128 + k) * 256 + c];
        q += psq [((size_t)t * 128 + k) * 256 + c];
    }
    __shared__ float ls[4][64], lq[4][64];
    ls[grp][cl] = s; lq[grp][cl] = q;
    __syncthreads();
    if (tid < 64) {
        s = ls[0][cl] + ls[1][cl] + ls[2][cl] + ls[3][cl];
        q = lq[0][cl] + lq[1][cl] + lq[2][cl] + lq[3][cl];
        float mean = s * (1.f / (float)M_);
        float var  = q * (1.f / (float)M_) - mean * mean;
        float inv  = rsqrtf(var + 1e-5f);
        float g = (t ? gc : gp)[c], be = (t ? bec : bep)[c];
        float sc = g * inv;
        ss[layerOff + t * 256 + c]       = sc;
        ss[layerOff + 512 + t * 256 + c] = be - mean * sc;
    }
}

// ---------------------------------------------------------------- GEMM2 (prefetch dbuf)
__global__ __launch_bounds__(512, 2) void gemm2f_kernel(
    const unsigned short* __restrict__ Y1,
    const unsigned short* __restrict__ Wb2,
    const float* __restrict__ ss,
    unsigned short* __restrict__ y2b,
    float* __restrict__ psum, float* __restrict__ psq)
{
    const int t  = blockIdx.y;
    const int m0 = blockIdx.x * 256;
    const unsigned short* Aw = Wb2 + (size_t)t * (OC_ * OC_);
    const unsigned short* By = Y1 + (size_t)t * M_ * OC_;

    __shared__ __align__(16) char smem[131072];
    __shared__ float Slds[256], Hlds[256];

    const int tid  = threadIdx.x;
    const int lane = tid & 63;
    const int wid  = tid >> 6;
    const int wc   = wid & 3;
    const int wm   = wid >> 2;
    const int srow = tid >> 3;
    const int k8   = (tid & 7) * 8;
    const int sk   = ((tid & 7) ^ (srow & 7)) * 8;
    const int kgrp = (lane >> 4) * 16;

    if (tid < 256) { Slds[tid] = ss[t * 256 + tid]; Hlds[tid] = ss[512 + t * 256 + tid]; }
    __syncthreads();

    f32x4 acc[4][8];
#pragma unroll
    for (int i = 0; i < 4; ++i)
#pragma unroll
        for (int j = 0; j < 8; ++j) acc[i][j] = f32x4{0.f, 0.f, 0.f, 0.f};

    auto stageA = [&](int buf, int kc) {
#pragma unroll
        for (int p = 0; p < 4; ++p)
            gload16(Aw + (size_t)(p * 64 + srow) * OC_ + kc + sk,
                    smem + buf * 32768 + p * 8192 + wid * 1024);
    };
    auto stageBY = [&](int buf, int kc) {
#pragma unroll
        for (int p = 0; p < 4; ++p) {
            int row = p * 64 + srow;
            ush8 yv = *(const ush8*)(By + (size_t)(m0 + row) * OC_ + kc + k8);
            ush8 ov;
#pragma unroll
            for (int j = 0; j < 8; ++j) {
                float y = bf2f(yv[j]);
                ov[j] = bf16rne(fmaxf(0.f, fmaf(y, Slds[kc + k8 + j], Hlds[kc + k8 + j])));
            }
            *(ush8*)(smem + 65536 + buf * 32768 + row * 128
                     + ((k8 * 2) ^ ((row & 7) << 4))) = ov;
        }
    };
    auto compute = [&](int buf) {
#pragma unroll
        for (int kk = 0; kk < 2; ++kk) {
            sh8 a[4], b[8];
#pragma unroll
            for (int f = 0; f < 4; ++f) {
                int ra = wc * 64 + (lane & 15) + f * 16;
                a[f] = *(const sh8*)(smem + buf * 32768 + ra * 128
                        + ((kk * 64 + kgrp) ^ ((ra & 7) << 4)));
            }
#pragma unroll
            for (int f = 0; f < 8; ++f) {
                int rb = wm * 128 + (lane & 15) + f * 16;
                b[f] = *(const sh8*)(smem + 65536 + buf * 32768 + rb * 128
                        + ((kk * 64 + kgrp) ^ ((rb & 7) << 4)));
            }
#pragma unroll
            for (int fc = 0; fc < 4; ++fc)
#pragma unroll
                for (int fm = 0; fm < 8; ++fm)
                    acc[fc][fm] = __builtin_amdgcn_mfma_f32_16x16x32_bf16(
                        a[fc], b[fm], acc[fc][fm], 0, 0, 0);
        }
    };

    stageA(0, 0); stageBY(0, 0);
    __syncthreads();
    int cur = 0;
    for (int step = 0; step < 4; ++step) {
        int kcn = (step + 1) * 64;
        if (step < 3) { stageA(cur ^ 1, kcn); stageBY(cur ^ 1, kcn); }
        compute(cur);
        __syncthreads();
        cur ^= 1;
    }

    const int mrow = m0 + wm * 128 + (lane & 15);
    const int chq  = (lane >> 4) * 4;
#pragma unroll
    for (int fm = 0; fm < 8; ++fm)
#pragma unroll
        for (int fc = 0; fc < 4; ++fc) {
            ush4 v;
#pragma unroll
            for (int r = 0; r < 4; ++r) v[r] = bf16rne(acc[fc][fm][r]);
            *(ush4*)(y2b + ((size_t)t * M_ + mrow + fm * 16) * OC_
                      + wc * 64 + fc * 16 + chq) = v;
        }

    float* sArr = (float*)smem;
    const int contrib = wm * 16 + (lane & 15);
#pragma unroll
    for (int ph = 0; ph < 2; ++ph) {
#pragma unroll
        for (int fc = 0; fc < 4; ++fc) {
            f32x4 s4;
#pragma unroll
            for (int r = 0; r < 4; ++r) {
                float s = 0.f;
#pragma unroll
                for (int fm = 0; fm < 8; ++fm) { float v = acc[fc][fm][r]; s += ph ? v * v : v; }
                s4[r] = s;
            }
            *(f32x4*)&sArr[contrib * 264 + wc * 64 + fc * 16 + chq] = s4;
        }
        __syncthreads();
        if (tid < 256) {
            float s = 0.f;
#pragma unroll
            for (int k = 0; k < 32; ++k) s += sArr[((k + tid) & 31) * 264 + tid];
            (ph ? psq : psum)[((size_t)t * 128 + blockIdx.x) * 256 + tid] = s;
        }
        __syncthreads();
    }
}

// ---------------------------------------------------------------- BN+ReLU + transpose
__global__ __launch_bounds__(256) void bnT_kernel(
    const unsigned short* __restrict__ y2b, const float* __restrict__ ss,
    float* __restrict__ out)
{
    const int z = blockIdx.z;
    const int t = z >> 3, b = z & 7;
    const int o0 = blockIdx.y * 64;
    const int n0 = blockIdx.x * 64;
    const int tid = threadIdx.x;
    __shared__ unsigned short tile[64][72];

    const unsigned short* src = y2b + ((size_t)t * M_ + (size_t)b * N_ + n0) * OC_ + o0;
#pragma unroll
    for (int it = 0; it < 2; ++it) {
        int u = it * 256 + tid;
        int m_l = u >> 3, o8 = (u & 7) * 8;
        *(ush8*)&tile[m_l][o8] = *(const ush8*)(src + (size_t)m_l * OC_ + o8);
    }
    __syncthreads();
#pragma unroll
    for (int it = 0; it < 4; ++it) {
        int v = it * 256 + tid;
        int o_l = v >> 4, n4 = (v & 15) * 4;
        int o = o0 + o_l;
        float sc = ss[1024 + t * 256 + o];
        float sh = ss[1536 + t * 256 + o];
        float4 w;
        w.x = fmaxf(0.f, fmaf(bf2f(tile[n4][o_l]),     sc, sh));
        w.y = fmaxf(0.f, fmaf(bf2f(tile[n4 + 1][o_l]), sc, sh));
        w.z = fmaxf(0.f, fmaf(bf2f(tile[n4 + 2][o_l]), sc, sh));
        w.w = fmaxf(0.f, fmaf(bf2f(tile[n4 + 3][o_l]), sc, sh));
        *(float4*)(out + (((size_t)t * B_ + b) * OC_ + o) * N_ + n0 + n4) = w;
    }
}

// ---------------------------------------------------------------- launch
extern "C" void kernel_launch(void* const* d_in, const int* in_sizes, int n_in,
                              void* d_out, int out_size, void* d_ws, size_t ws_size,
                              hipStream_t stream)
{
    const float* xyz1    = (const float*)d_in[0];
    const float* xyz2    = (const float*)d_in[1];
    const float* points1 = (const float*)d_in[2];
    const float* points2 = (const float*)d_in[3];
    const float* colors1 = (const float*)d_in[4];
    const float* colors2 = (const float*)d_in[5];
    const float* Wp1  = (const float*)d_in[6];
    const float* gp1  = (const float*)d_in[8];
    const float* bep1 = (const float*)d_in[9];
    const float* Wc1  = (const float*)d_in[10];
    const float* gc1  = (const float*)d_in[12];
    const float* bec1 = (const float*)d_in[13];
    const float* Wp2  = (const float*)d_in[14];
    const float* gp2  = (const float*)d_in[16];
    const float* bep2 = (const float*)d_in[17];
    const float* Wc2  = (const float*)d_in[18];
    const float* gc2  = (const float*)d_in[20];
    const float* bec2 = (const float*)d_in[21];
    // biases (d_in[7,11,15,19]) unused: constant channel shift cancels in BN.

    char* ws = (char*)d_ws;
    unsigned short* y2b  = (unsigned short*)(ws + 0);
    unsigned short* Xp   = (unsigned short*)(ws + 0);         // overlays y2b
    unsigned short* p2b  = (unsigned short*)(ws + 16777216);
    unsigned short* c2b  = (unsigned short*)(ws + 20971520);
    int*   idxw = (int*)  (ws + 25165824);
    float* wgtw = (float*)(ws + 25559040);
    unsigned short* Y1   = (unsigned short*)(ws + 33554432);
    unsigned short* Wb1  = (unsigned short*)(ws + 67108864);
    unsigned short* Wb2  = (unsigned short*)(ws + 67895296);
    float* psum = (float*)(ws + 68419584);
    float* psq  = (float*)(ws + 68681728);
    float* ssb  = (float*)(ws + 68943872);
    float* out  = (float*)d_out;

    front_kernel<<<6464, 256, 0, stream>>>(xyz1, xyz2, points1, colors1,
                                           points2, colors2, Wp1, Wc1, Wp2, Wc2,
                                           idxw, wgtw, p2b, c2b, Wb1, Wb2, Xp);
    gemm1f_kernel<<<256, 512, 0, stream>>>(Xp, p2b, c2b, idxw, wgtw,
                                           Wb1, Y1, psum, psq);
    reduce_kernel<<<dim3(2, 4), 256, 0, stream>>>(psum, psq, gp1, bep1, gc1, bec1, ssb, 0);
    gemm2f_kernel<<<dim3(128, 2), 512, 0, stream>>>(Y1, Wb2, ssb, y2b, psum, psq);
    reduce_kernel<<<dim3(2, 4), 256, 0, stream>>>(psum, psq, gp2, bep2, gc2, bec2, ssb, 1024);
    bnT_kernel<<<dim3(64, 4, 16), 256, 0, stream>>>(y2b, ssb, out);
}

// Round 9
// 113.559 us; speedup vs baseline: 1.0051x; 1.0051x over previous
//
#include <hip/hip_runtime.h>
#include <cstdint>
#include <cstddef>

// PointNet++ FP, bf16-MFMA pipeline v6: occupancy-slim front.
// B=8, N=4096, S=1024, D1=128, D2=256, IN_C=384, MLP=[256,256], BN training.
//
//  front:  ONE kernel (17.7 KB LDS -> 8 blocks/CU), block-role dispatch:
//            [0,1024)      top3 (8 lanes/query, branchless + shfl_xor merge)
//            [1024,3072)   transpose points2 -> p2b bf16 [B][S][256]
//            [3072,5120)   transpose colors2 -> c2b bf16
//            [5120,5440)   convw: W* -> bf16 [o][k]
//            [5440,6464)   buildxA: points1/colors1 -> Xp bf16 (2-phase, 69-pad)
//  gemm1f: 256m x 256c, 8 waves, LDS dbuf prefetch; xcd=wg&7, t=xcd&1
//  reduce(0); gemm2f: B = relu(bn(Y1)); y2b bf16 + stats; reduce(1024)
//  bnT: LDS-transpose + relu(bn) -> d_out [t][b][o][n] fp32
//
// ws layout (bytes), total 68,952,064:
//   y2b @0 (33.5M) overlays: Xp@0 | p2b@16777216 | c2b@20971520
//     | idxw@25165824 | wgtw@25559040
//   Y1 @33554432 | Wb1 @67108864 | Wb2 @67895296
//   psum @68419584 | psq @68681728 | ssb @68943872

#define B_   8
#define N_   4096
#define S_   1024
#define D1_  128
#define D2_  256
#define INC_ 384
#define OC_  256
#define M_   (B_ * N_)

typedef __attribute__((ext_vector_type(8))) short sh8;
typedef __attribute__((ext_vector_type(4))) float f32x4;
typedef __attribute__((ext_vector_type(4))) unsigned short ush4;
typedef __attribute__((ext_vector_type(8))) unsigned short ush8;

__device__ __forceinline__ unsigned short bf16rne(float f) {
    union { float f; unsigned u; } v; v.f = f;
    return (unsigned short)((v.u + 0x7FFFu + ((v.u >> 16) & 1u)) >> 16);
}
__device__ __forceinline__ float bf2f(unsigned short h) {
    union { unsigned u; float f; } v; v.u = ((unsigned)h) << 16;
    return v.f;
}
__device__ __forceinline__ void gload16(const void* gsrc, void* lds) {
    __builtin_amdgcn_global_load_lds(
        (const __attribute__((address_space(1))) void*)gsrc,
        (__attribute__((address_space(3))) void*)lds, 16, 0, 0);
}

// ---------------------------------------------------------------- front
#define INS(pd, pi) { \
    bool l0 = (pd < d0) || (pd == d0 && pi < i0); \
    bool l1 = (pd < d1) || (pd == d1 && pi < i1); \
    bool l2 = (pd < d2) || (pd == d2 && pi < i2); \
    d2 = l1 ? d1 : (l2 ? pd : d2);  i2 = l1 ? i1 : (l2 ? pi : i2); \
    d1 = l0 ? d0 : (l1 ? pd : d1);  i1 = l0 ? i0 : (l1 ? pi : i1); \
    d0 = l0 ? pd : d0;              i0 = l0 ? pi : i0; \
}

__global__ __launch_bounds__(256) void front_kernel(
    const float* __restrict__ xyz1, const float* __restrict__ xyz2,
    const float* __restrict__ points1, const float* __restrict__ colors1,
    const float* __restrict__ points2, const float* __restrict__ colors2,
    const float* __restrict__ Wp1, const float* __restrict__ Wc1,
    const float* __restrict__ Wp2, const float* __restrict__ Wc2,
    int* __restrict__ idxo, float* __restrict__ wo,
    unsigned short* __restrict__ p2b, unsigned short* __restrict__ c2b,
    unsigned short* __restrict__ Wb1, unsigned short* __restrict__ Wb2,
    unsigned short* __restrict__ Xp)
{
    __shared__ __align__(16) char fsm[17664];   // max(top3 16K, tileA 64*69*4)
    const int bid = blockIdx.x;
    const int tid = threadIdx.x;

    if (bid < 1024) {
        // ---- top-3 NN (critical path first)
        float4* sc = (float4*)fsm;
        const int b = bid >> 7, qb = bid & 127;
        const float* x2 = xyz2 + (size_t)b * 3 * S_;
        for (int s = tid; s < S_; s += 256) {
            float xs = x2[s], ys = x2[S_ + s], zs = x2[2 * S_ + s];
            sc[s] = make_float4(xs, ys, zs, xs * xs + ys * ys + zs * zs);
        }
        __syncthreads();
        const int q = qb * 32 + (tid >> 3);
        const int sub = tid & 7;
        const float* x1 = xyz1 + (size_t)b * 3 * N_;
        const float xq = x1[q], yq = x1[N_ + q], zq = x1[2 * N_ + q];
        const float n1 = xq * xq + yq * yq + zq * zq;
        float d0 = 3.4e38f, d1 = 3.4e38f, d2 = 3.4e38f;
        int i0 = 0, i1 = 0, i2 = 0;
#pragma unroll 4
        for (int j = 0; j < 128; ++j) {
            int s = j * 8 + sub;
            float4 v = sc[s];
            float dot = xq * v.x + yq * v.y + zq * v.z;
            float d = (n1 - 2.0f * dot) + v.w;
            bool c0 = d < d0, c1 = d < d1, c2 = d < d2;
            d2 = c1 ? d1 : (c2 ? d : d2); i2 = c1 ? i1 : (c2 ? s : i2);
            d1 = c0 ? d0 : (c1 ? d : d1); i1 = c0 ? i0 : (c1 ? s : i1);
            d0 = c0 ? d : d0;             i0 = c0 ? s : i0;
        }
#pragma unroll
        for (int off = 1; off < 8; off <<= 1) {
            float pd0 = __shfl_xor(d0, off), pd1 = __shfl_xor(d1, off), pd2 = __shfl_xor(d2, off);
            int   pi0 = __shfl_xor(i0, off), pi1 = __shfl_xor(i1, off), pi2 = __shfl_xor(i2, off);
            INS(pd0, pi0) INS(pd1, pi1) INS(pd2, pi2)
        }
        if (sub == 0) {
            float r0 = 1.f / (d0 + 1e-8f);
            float r1 = 1.f / (d1 + 1e-8f);
            float r2 = 1.f / (d2 + 1e-8f);
            float rs = r0 + r1 + r2;
            int base = (b * N_ + q) * 3;
            idxo[base] = i0; idxo[base + 1] = i1; idxo[base + 2] = i2;
            wo[base] = r0 / rs; wo[base + 1] = r1 / rs; wo[base + 2] = r2 / rs;
        }
    } else if (bid < 5120) {
        // ---- transpose points2/colors2 -> bf16 [B][S][256]
        float (*tile)[33] = (float(*)[33])fsm;
        const int u = bid - 1024;
        const int which = u >> 11;                 // 0: points2, 1: colors2
        const int v = u & 2047;
        const int z = v >> 8, rem = v & 255;
        const int cx = rem & 31, ry = rem >> 5;
        const int tx = tid & 31, ty = tid >> 5;
        const float* s = (which ? colors2 : points2) + (size_t)z * D2_ * S_;
        unsigned short* d = (which ? c2b : p2b) + (size_t)z * S_ * D2_;
#pragma unroll
        for (int i = 0; i < 4; ++i)
            tile[ty + i * 8][tx] = s[(size_t)(ry * 32 + ty + i * 8) * S_ + cx * 32 + tx];
        __syncthreads();
#pragma unroll
        for (int i = 0; i < 4; ++i)
            d[(size_t)(cx * 32 + ty + i * 8) * D2_ + ry * 32 + tx] =
                bf16rne(tile[tx][ty + i * 8]);
    } else if (bid < 5440) {
        // ---- convw
        int e = ((bid - 5120) * 256 + tid) * 4;
        const float* src; unsigned short* dst; int off;
        if (e < 98304)       { src = Wp1; dst = Wb1;          off = e; }
        else if (e < 196608) { src = Wc1; dst = Wb1 + 98304;  off = e - 98304; }
        else if (e < 262144) { src = Wp2; dst = Wb2;          off = e - 196608; }
        else                 { src = Wc2; dst = Wb2 + 65536;  off = e - 262144; }
        float4 v = *(const float4*)(src + off);
        ush4 o; o[0] = bf16rne(v.x); o[1] = bf16rne(v.y); o[2] = bf16rne(v.z); o[3] = bf16rne(v.w);
        *(ush4*)(dst + off) = o;
    } else {
        // ---- buildxA: transpose points1/colors1 -> Xp bf16, 2-phase (64 d each)
        float (*tileA)[69] = (float(*)[69])fsm;
        const int u = bid - 5440;
        const int t = u >> 9, rem = u & 511;
        const int b = rem >> 6, n0 = (rem & 63) * 64;
        const float* x1 = t ? colors1 : points1;
        size_t mbase = (size_t)t * M_ + (size_t)b * N_ + n0;
#pragma unroll
        for (int ph = 0; ph < 2; ++ph) {
            if (ph) __syncthreads();
#pragma unroll
            for (int it = 0; it < 4; ++it) {
                int fl4 = it * 256 + tid;
                int dl = fl4 >> 4, nl = (fl4 & 15) * 4;
                float4 v = *(const float4*)(x1 + ((size_t)b * D1_ + ph * 64 + dl) * N_ + n0 + nl);
                tileA[nl][dl] = v.x; tileA[nl + 1][dl] = v.y;
                tileA[nl + 2][dl] = v.z; tileA[nl + 3][dl] = v.w;
            }
            __syncthreads();
#pragma unroll
            for (int it = 0; it < 2; ++it) {
                int e8 = it * 256 + tid;
                int r = e8 >> 3, dc = (e8 & 7) * 8;
                ush8 o;
#pragma unroll
                for (int j = 0; j < 8; ++j) o[j] = bf16rne(tileA[r][dc + j]);
                *(ush8*)(Xp + (mbase + r) * D1_ + ph * 64 + dc) = o;
            }
        }
    }
}

// ---------------------------------------------------------------- GEMM1 (prefetch dbuf)
// 1-D grid 256; xcd = wg&7, t = xcd&1 -> per-XCD L2 caches one gather tensor.
__global__ __launch_bounds__(512, 2) void gemm1f_kernel(
    const unsigned short* __restrict__ Xp,
    const unsigned short* __restrict__ p2b,
    const unsigned short* __restrict__ c2b,
    const int* __restrict__ idxw, const float* __restrict__ wgtw,
    const unsigned short* __restrict__ Wb1,
    unsigned short* __restrict__ Y1,
    float* __restrict__ psum, float* __restrict__ psq)
{
    const int wg  = blockIdx.x;
    const int xcd = wg & 7;
    const int t   = xcd & 1;
    const int mt  = (xcd >> 1) * 32 + (wg >> 3);   // 0..127, bijective
    const int m0  = mt * 256;
    const int bb  = m0 >> 12;
    const unsigned short* Aw  = Wb1 + (size_t)t * (OC_ * INC_);
    const unsigned short* Xb  = Xp + (size_t)t * M_ * D1_;
    const unsigned short* f2b = t ? c2b : p2b;

    __shared__ __align__(16) char smem[131072];

    const int tid  = threadIdx.x;
    const int lane = tid & 63;
    const int wid  = tid >> 6;
    const int wc   = wid & 3;
    const int wm   = wid >> 2;
    const int srow = tid >> 3;
    const int k8   = (tid & 7) * 8;
    const int sk   = ((tid & 7) ^ (srow & 7)) * 8;
    const int kgrp = (lane >> 4) * 16;

    int gi[4][3]; float gw[4][3];
#pragma unroll
    for (int p = 0; p < 4; ++p) {
        int base = (m0 + p * 64 + srow) * 3;
#pragma unroll
        for (int j = 0; j < 3; ++j) { gi[p][j] = idxw[base + j]; gw[p][j] = wgtw[base + j]; }
    }

    f32x4 acc[4][8];
#pragma unroll
    for (int i = 0; i < 4; ++i)
#pragma unroll
        for (int j = 0; j < 8; ++j) acc[i][j] = f32x4{0.f, 0.f, 0.f, 0.f};

    auto stageA = [&](int buf, int kc) {
#pragma unroll
        for (int p = 0; p < 4; ++p)
            gload16(Aw + (size_t)(p * 64 + srow) * INC_ + kc + sk,
                    smem + buf * 32768 + p * 8192 + wid * 1024);
    };
    auto stageBX = [&](int buf, int kc) {
#pragma unroll
        for (int p = 0; p < 4; ++p)
            gload16(Xb + (size_t)(m0 + p * 64 + srow) * D1_ + kc + sk,
                    smem + 65536 + buf * 32768 + p * 8192 + wid * 1024);
    };
    auto stageBG = [&](int buf, int kc) {
        const int d0k = kc - D1_ + k8;
#pragma unroll
        for (int p = 0; p < 4; ++p) {
            int row = p * 64 + srow;
            ush8 a0 = *(const ush8*)(f2b + ((size_t)bb * S_ + gi[p][0]) * D2_ + d0k);
            ush8 a1 = *(const ush8*)(f2b + ((size_t)bb * S_ + gi[p][1]) * D2_ + d0k);
            ush8 a2 = *(const ush8*)(f2b + ((size_t)bb * S_ + gi[p][2]) * D2_ + d0k);
            ush8 ov;
#pragma unroll
            for (int j = 0; j < 8; ++j)
                ov[j] = bf16rne(gw[p][0] * bf2f(a0[j]) + gw[p][1] * bf2f(a1[j])
                              + gw[p][2] * bf2f(a2[j]));
            *(ush8*)(smem + 65536 + buf * 32768 + row * 128
                     + ((k8 * 2) ^ ((row & 7) << 4))) = ov;
        }
    };
    auto compute = [&](int buf) {
#pragma unroll
        for (int kk = 0; kk < 2; ++kk) {
            sh8 a[4], b[8];
#pragma unroll
            for (int f = 0; f < 4; ++f) {
                int ra = wc * 64 + (lane & 15) + f * 16;
                a[f] = *(const sh8*)(smem + buf * 32768 + ra * 128
                        + ((kk * 64 + kgrp) ^ ((ra & 7) << 4)));
            }
#pragma unroll
            for (int f = 0; f < 8; ++f) {
                int rb = wm * 128 + (lane & 15) + f * 16;
                b[f] = *(const sh8*)(smem + 65536 + buf * 32768 + rb * 128
                        + ((kk * 64 + kgrp) ^ ((rb & 7) << 4)));
            }
#pragma unroll
            for (int fc = 0; fc < 4; ++fc)
#pragma unroll
                for (int fm = 0; fm < 8; ++fm)
                    acc[fc][fm] = __builtin_amdgcn_mfma_f32_16x16x32_bf16(
                        a[fc], b[fm], acc[fc][fm], 0, 0, 0);
        }
    };

    stageA(0, 0); stageBX(0, 0);
    __syncthreads();
    int cur = 0;
    for (int step = 0; step < 6; ++step) {
        int kcn = (step + 1) * 64;
        if (step < 5) {
            stageA(cur ^ 1, kcn);
            if (kcn < D1_) stageBX(cur ^ 1, kcn);
            else           stageBG(cur ^ 1, kcn);
        }
        compute(cur);
        __syncthreads();
        cur ^= 1;
    }

    const int mrow = m0 + wm * 128 + (lane & 15);
    const int chq  = (lane >> 4) * 4;
#pragma unroll
    for (int fm = 0; fm < 8; ++fm)
#pragma unroll
        for (int fc = 0; fc < 4; ++fc) {
            ush4 v;
#pragma unroll
            for (int r = 0; r < 4; ++r) v[r] = bf16rne(acc[fc][fm][r]);
            *(ush4*)(Y1 + ((size_t)t * M_ + mrow + fm * 16) * OC_
                      + wc * 64 + fc * 16 + chq) = v;
        }

    float* sArr = (float*)smem;
    const int contrib = wm * 16 + (lane & 15);
#pragma unroll
    for (int ph = 0; ph < 2; ++ph) {
#pragma unroll
        for (int fc = 0; fc < 4; ++fc) {
            f32x4 s4;
#pragma unroll
            for (int r = 0; r < 4; ++r) {
                float s = 0.f;
#pragma unroll
                for (int fm = 0; fm < 8; ++fm) { float v = acc[fc][fm][r]; s += ph ? v * v : v; }
                s4[r] = s;
            }
            *(f32x4*)&sArr[contrib * 264 + wc * 64 + fc * 16 + chq] = s4;
        }
        __syncthreads();
        if (tid < 256) {
            float s = 0.f;
#pragma unroll
            for (int k = 0; k < 32; ++k) s += sArr[((k + tid) & 31) * 264 + tid];
            (ph ? psq : psum)[((size_t)t * 128 + mt) * 256 + tid] = s;
        }
        __syncthreads();
    }
}

// ---------------------------------------------------------------- stats reduce
__global__ __launch_bounds__(256) void reduce_kernel(
    const float* __restrict__ psum, const float* __restrict__ psq,
    const float* __restrict__ gp, const float* __restrict__ bep,
    const float* __restrict__ gc, const float* __restrict__ bec,
    float* __restrict__ ss, int layerOff)
{
    const int t = blockIdx.x, cs = blockIdx.y;
    const int tid = threadIdx.x;
    const int cl = tid & 63, grp = tid >> 6;
    const int c = cs * 64 + cl;
    float s = 0.f, q = 0.f;
    for (int k = grp; k < 128; k += 4) {
        s += psum[((size_t)t * 128 + k) * 256 + c];
        q += psq [((size_t)t * 128 + k) * 256 + c];
    }
    __shared__ float ls[4][64], lq[4][64];
    ls[grp][cl] = s; lq[grp][cl] = q;
    __syncthreads();
    if (tid < 64) {
        s = ls[0][cl] + ls[1][cl] + ls[2][cl] + ls[3][cl];
        q = lq[0][cl] + lq[1][cl] + lq[2][cl] + lq[3][cl];
        float mean = s * (1.f / (float)M_);
        float var  = q * (1.f / (float)M_) - mean * mean;
        float inv  = rsqrtf(var + 1e-5f);
        float g = (t ? gc : gp)[c], be = (t ? bec : bep)[c];
        float sc = g * inv;
        ss[layerOff + t * 256 + c]       = sc;
        ss[layerOff + 512 + t * 256 + c] = be - mean * sc;
    }
}

// ---------------------------------------------------------------- GEMM2 (prefetch dbuf)
__global__ __launch_bounds__(512, 2) void gemm2f_kernel(
    const unsigned short* __restrict__ Y1,
    const unsigned short* __restrict__ Wb2,
    const float* __restrict__ ss,
    unsigned short* __restrict__ y2b,
    float* __restrict__ psum, float* __restrict__ psq)
{
    const int t  = blockIdx.y;
    const int m0 = blockIdx.x * 256;
    const unsigned short* Aw = Wb2 + (size_t)t * (OC_ * OC_);
    const unsigned short* By = Y1 + (size_t)t * M_ * OC_;

    __shared__ __align__(16) char smem[131072];
    __shared__ float Slds[256], Hlds[256];

    const int tid  = threadIdx.x;
    const int lane = tid & 63;
    const int wid  = tid >> 6;
    const int wc   = wid & 3;
    const int wm   = wid >> 2;
    const int srow = tid >> 3;
    const int k8   = (tid & 7) * 8;
    const int sk   = ((tid & 7) ^ (srow & 7)) * 8;
    const int kgrp = (lane >> 4) * 16;

    if (tid < 256) { Slds[tid] = ss[t * 256 + tid]; Hlds[tid] = ss[512 + t * 256 + tid]; }
    __syncthreads();

    f32x4 acc[4][8];
#pragma unroll
    for (int i = 0; i < 4; ++i)
#pragma unroll
        for (int j = 0; j < 8; ++j) acc[i][j] = f32x4{0.f, 0.f, 0.f, 0.f};

    auto stageA = [&](int buf, int kc) {
#pragma unroll
        for (int p = 0; p < 4; ++p)
            gload16(Aw + (size_t)(p * 64 + srow) * OC_ + kc + sk,
                    smem + buf * 32768 + p * 8192 + wid * 1024);
    };
    auto stageBY = [&](int buf, int kc) {
#pragma unroll
        for (int p = 0; p < 4; ++p) {
            int row = p * 64 + srow;
            ush8 yv = *(const ush8*)(By + (size_t)(m0 + row) * OC_ + kc + k8);
            ush8 ov;
#pragma unroll
            for (int j = 0; j < 8; ++j) {
                float y = bf2f(yv[j]);
                ov[j] = bf16rne(fmaxf(0.f, fmaf(y, Slds[kc + k8 + j], Hlds[kc + k8 + j])));
            }
            *(ush8*)(smem + 65536 + buf * 32768 + row * 128
                     + ((k8 * 2) ^ ((row & 7) << 4))) = ov;
        }
    };
    auto compute = [&](int buf) {
#pragma unroll
        for (int kk = 0; kk < 2; ++kk) {
            sh8 a[4], b[8];
#pragma unroll
            for (int f = 0; f < 4; ++f) {
                int ra = wc * 64 + (lane & 15) + f * 16;
                a[f] = *(const sh8*)(smem + buf * 32768 + ra * 128
                        + ((kk * 64 + kgrp) ^ ((ra & 7) << 4)));
            }
#pragma unroll
            for (int f = 0; f < 8; ++f) {
                int rb = wm * 128 + (lane & 15) + f * 16;
                b[f] = *(const sh8*)(smem + 65536 + buf * 32768 + rb * 128
                        + ((kk * 64 + kgrp) ^ ((rb & 7) << 4)));
            }
#pragma unroll
            for (int fc = 0; fc < 4; ++fc)
#pragma unroll
                for (int fm = 0; fm < 8; ++fm)
                    acc[fc][fm] = __builtin_amdgcn_mfma_f32_16x16x32_bf16(
                        a[fc], b[fm], acc[fc][fm], 0, 0, 0);
        }
    };

    stageA(0, 0); stageBY(0, 0);
    __syncthreads();
    int cur = 0;
    for (int step = 0; step < 4; ++step) {
        int kcn = (step + 1) * 64;
        if (step < 3) { stageA(cur ^ 1, kcn); stageBY(cur ^ 1, kcn); }
        compute(cur);
        __syncthreads();
        cur ^= 1;
    }

    const int mrow = m0 + wm * 128 + (lane & 15);
    const int chq  = (lane >> 4) * 4;
#pragma unroll
    for (int fm = 0; fm < 8; ++fm)
#pragma unroll
        for (int fc = 0; fc < 4; ++fc) {
            ush4 v;
#pragma unroll
            for (int r = 0; r < 4; ++r) v[r] = bf16rne(acc[fc][fm][r]);
            *(ush4*)(y2b + ((size_t)t * M_ + mrow + fm * 16) * OC_
                      + wc * 64 + fc * 16 + chq) = v;
        }

    float* sArr = (float*)smem;
    const int contrib = wm * 16 + (lane & 15);
#pragma unroll
    for (int ph = 0; ph < 2; ++ph) {
#pragma unroll
        for (int fc = 0; fc < 4; ++fc) {
            f32x4 s4;
#pragma unroll
            for (int r = 0; r < 4; ++r) {
                float s = 0.f;
#pragma unroll
                for (int fm = 0; fm < 8; ++fm) { float v = acc[fc][fm][r]; s += ph ? v * v : v; }
                s4[r] = s;
            }
            *(f32x4*)&sArr[contrib * 264 + wc * 64 + fc * 16 + chq] = s4;
        }
        __syncthreads();
        if (tid < 256) {
            float s = 0.f;
#pragma unroll
            for (int k = 0; k < 32; ++k) s += sArr[((k + tid) & 31) * 264 + tid];
            (ph ? psq : psum)[((size_t)t * 128 + blockIdx.x) * 256 + tid] = s;
        }
        __syncthreads();
    }
}

// ---------------------------------------------------------------- BN+ReLU + transpose
__global__ __launch_bounds__(256) void bnT_kernel(
    const unsigned short* __restrict__ y2b, const float* __restrict__ ss,
    float* __restrict__ out)
{
    const int z = blockIdx.z;
    const int t = z >> 3, b = z & 7;
    const int o0 = blockIdx.y * 64;
    const int n0 = blockIdx.x * 64;
    const int tid = threadIdx.x;
    __shared__ unsigned short tile[64][72];

    const unsigned short* src = y2b + ((size_t)t * M_ + (size_t)b * N_ + n0) * OC_ + o0;
#pragma unroll
    for (int it = 0; it < 2; ++it) {
        int u = it * 256 + tid;
        int m_l = u >> 3, o8 = (u & 7) * 8;
        *(ush8*)&tile[m_l][o8] = *(const ush8*)(src + (size_t)m_l * OC_ + o8);
    }
    __syncthreads();
#pragma unroll
    for (int it = 0; it < 4; ++it) {
        int v = it * 256 + tid;
        int o_l = v >> 4, n4 = (v & 15) * 4;
        int o = o0 + o_l;
        float sc = ss[1024 + t * 256 + o];
        float sh = ss[1536 + t * 256 + o];
        float4 w;
        w.x = fmaxf(0.f, fmaf(bf2f(tile[n4][o_l]),     sc, sh));
        w.y = fmaxf(0.f, fmaf(bf2f(tile[n4 + 1][o_l]), sc, sh));
        w.z = fmaxf(0.f, fmaf(bf2f(tile[n4 + 2][o_l]), sc, sh));
        w.w = fmaxf(0.f, fmaf(bf2f(tile[n4 + 3][o_l]), sc, sh));
        *(float4*)(out + (((size_t)t * B_ + b) * OC_ + o) * N_ + n0 + n4) = w;
    }
}

// ---------------------------------------------------------------- launch
extern "C" void kernel_launch(void* const* d_in, const int* in_sizes, int n_in,
                              void* d_out, int out_size, void* d_ws, size_t ws_size,
                              hipStream_t stream)
{
    const float* xyz1    = (const float*)d_in[0];
    const float* xyz2    = (const float*)d_in[1];
    const float* points1 = (const float*)d_in[2];
    const float* points2 = (const float*)d_in[3];
    const float* colors1 = (const float*)d_in[4];
    const float* colors2 = (const float*)d_in[5];
    const float* Wp1  = (const float*)d_in[6];
    const float* gp1  = (const float*)d_in[8];
    const float* bep1 = (const float*)d_in[9];
    const float* Wc1  = (const float*)d_in[10];
    const float* gc1  = (const float*)d_in[12];
    const float* bec1 = (const float*)d_in[13];
    const float* Wp2  = (const float*)d_in[14];
    const float* gp2  = (const float*)d_in[16];
    const float* bep2 = (const float*)d_in[17];
    const float* Wc2  = (const float*)d_in[18];
    const float* gc2  = (const float*)d_in[20];
    const float* bec2 = (const float*)d_in[21];
    // biases (d_in[7,11,15,19]) unused: constant channel shift cancels in BN.

    char* ws = (char*)d_ws;
    unsigned short* y2b  = (unsigned short*)(ws + 0);
    unsigned short* Xp   = (unsigned short*)(ws + 0);         // overlays y2b
    unsigned short* p2b  = (unsigned short*)(ws + 16777216);
    unsigned short* c2b  = (unsigned short*)(ws + 20971520);
    int*   idxw = (int*)  (ws + 25165824);
    float* wgtw = (float*)(ws + 25559040);
    unsigned short* Y1   = (unsigned short*)(ws + 33554432);
    unsigned short* Wb1  = (unsigned short*)(ws + 67108864);
    unsigned short* Wb2  = (unsigned short*)(ws + 67895296);
    float* psum = (float*)(ws + 68419584);
    float* psq  = (float*)(ws + 68681728);
    float* ssb  = (float*)(ws + 68943872);
    float* out  = (float*)d_out;

    front_kernel<<<6464, 256, 0, stream>>>(xyz1, xyz2, points1, colors1,
                                           points2, colors2, Wp1, Wc1, Wp2, Wc2,
                                           idxw, wgtw, p2b, c2b, Wb1, Wb2, Xp);
    gemm1f_kernel<<<256, 512, 0, stream>>>(Xp, p2b, c2b, idxw, wgtw,
                                           Wb1, Y1, psum, psq);
    reduce_kernel<<<dim3(2, 4), 256, 0, stream>>>(psum, psq, gp1, bep1, gc1, bec1, ssb, 0);
    gemm2f_kernel<<<dim3(128, 2), 512, 0, stream>>>(Y1, Wb2, ssb, y2b, psum, psq);
    reduce_kernel<<<dim3(2, 4), 256, 0, stream>>>(psum, psq, gp2, bep2, gc2, bec2, ssb, 1024);
    bnT_kernel<<<dim3(64, 4, 16), 256, 0, stream>>>(y2b, ssb, out);
}